// Round 8
// baseline (472.270 us; speedup 1.0000x reference)
//
#include <hip/hip_runtime.h>

// ---------------------------------------------------------------------------
// RPN head on gfx950: x --conv3x3(512->256)+relu--> h1 --conv3x3(256->256)+relu
//   --> h2 --1x1 heads (cls 18 / reg 36)--> softmax pairs --> out (B,H,W,9,6)
// R9 = R8 (145 us conv1, 0 bank conflicts, coalesced staging) +
//  (A) ks-split counted lgkmcnt in the conv phase: pin ds_read issue order
//      (ks0 | sched_barrier | ks1), then lgkmcnt(6) -> MFMA(ks0) ->
//      lgkmcnt(0) -> MFMA(ks1).  Second half of the LDS drain overlaps the
//      first MFMA cluster; no extra registers (both sets already live in R8).
//  (B) convert_x rebuilt as LDS-transposed writer: coalesced NHWC reads
//      (lanes over channels), XOR-swizzled 32x64 LDS tile (g ^= px&7,
//      conflict-free both phases), granule-major writes with lanes over px
//      (512-B contiguous runs).  R8's version scattered 16-B writes at
//      2080-B stride (64 cache lines per wave store over 69 MB).
// ---------------------------------------------------------------------------

typedef float f32x4  __attribute__((ext_vector_type(4)));
typedef float f32x16 __attribute__((ext_vector_type(16)));
typedef short bf16x8 __attribute__((ext_vector_type(8)));   // 8 bf16 = 4 VGPRs

union U16x8 { uint4 v; unsigned short s[8]; };

__device__ __forceinline__ unsigned short f2bf(float f) {
  union { float f; unsigned int u; } v; v.f = f;
  unsigned int r = v.u + 0x7FFFu + ((v.u >> 16) & 1u);   // RNE
  return (unsigned short)(r >> 16);
}

#define GLOAD_LDS16(G, L)                                        \
  __builtin_amdgcn_global_load_lds(                              \
      (const __attribute__((address_space(1))) void*)(G),        \
      (__attribute__((address_space(3))) void*)(L), 16, 0, 0)

// ---- transpose + fp32->bf16: src[z][K][N] -> dst[z][N][K] (heads only) -----
__global__ __launch_bounds__(256) void transpose_cvt(
    const float* __restrict__ src, unsigned short* __restrict__ dst,
    int K, int N) {
  __shared__ float t[32][33];
  const int tx = threadIdx.x, ty = threadIdx.y;     // 32 x 8
  const int k0 = blockIdx.x * 32, n0 = blockIdx.y * 32;
  const float* s = src + (size_t)blockIdx.z * K * N;
  unsigned short* d = dst + (size_t)blockIdx.z * N * K;
#pragma unroll
  for (int r = 0; r < 32; r += 8) {
    int k = k0 + ty + r, n = n0 + tx;
    t[ty + r][tx] = (k < K && n < N) ? s[(size_t)k * N + n] : 0.f;
  }
  __syncthreads();
#pragma unroll
  for (int r = 0; r < 32; r += 8) {
    int n = n0 + ty + r, k = k0 + tx;
    if (n < N && k < K) d[(size_t)n * K + k] = f2bf(t[tx][ty + r]);
  }
}

// ---- pack conv weights (3,3,CIN,256) f32 -> per-tile LDS order bf16 --------
// out[(dy*NCI+kt)*24576 + ((dx*4+q)*256+co)*8 + e] = W[dy][dx][kt*32+q*8+e][co]
__global__ __launch_bounds__(256) void pack_w(
    const float* __restrict__ W, unsigned short* __restrict__ out, int CIN) {
  const int NCI = CIN / 32;
  int tid = blockIdx.x * 256 + threadIdx.x;        // 9*NCI*1024 total
  int co = tid & 255;
  int q  = (tid >> 8) & 3;
  int t  = tid >> 10;
  int dx = t % 3;
  int r  = t / 3;
  int kt = r % NCI;
  int dy = r / NCI;
  U16x8 u;
#pragma unroll
  for (int e = 0; e < 8; ++e) {
    int ci = kt * 32 + q * 8 + e;
    u.s[e] = f2bf(W[((size_t)(dy * 3 + dx) * CIN + ci) * 256 + co]);
  }
  *(uint4*)(out + (size_t)tid * 8) = u.v;
}

// ---- x (f32 NHWC) -> x_pad interior (bf16 granule-major [4][130][64][130][8])
// LDS-transposed: coalesced reads (lanes over g), coalesced writes (lanes
// over px, 512-B runs).  XOR swizzle g^=(px&7): conflict-free both phases.
__global__ __launch_bounds__(256) void convert_x_t(
    const float* __restrict__ x, unsigned short* __restrict__ xp) {
  __shared__ __align__(16) unsigned short t[32 * 64 * 8];   // 32 px x 64 g
  const int tid = threadIdx.x;
  const int blk = blockIdx.x;            // b*512 + y*4 + pxblk
  const int pxb = blk & 3;
  const int y   = (blk >> 2) & 127;      // interior row (ypix = y+1)
  const int b   = blk >> 9;
  const int px0 = pxb * 32 + 1;          // output px 1..128
  {
    const int g = tid & 63, pl = tid >> 6;   // pl 0..3
#pragma unroll
    for (int it = 0; it < 8; ++it) {
      int pxl = it * 4 + pl;                 // 0..31
      const float* sp = x + ((size_t)((b * 128 + y) * 128) + (px0 - 1 + pxl)) * 512 + g * 8;
      float4 a = *(const float4*)sp;
      float4 c = *(const float4*)(sp + 4);
      U16x8 u;
      u.s[0] = f2bf(a.x); u.s[1] = f2bf(a.y); u.s[2] = f2bf(a.z); u.s[3] = f2bf(a.w);
      u.s[4] = f2bf(c.x); u.s[5] = f2bf(c.y); u.s[6] = f2bf(c.z); u.s[7] = f2bf(c.w);
      *(uint4*)&t[((size_t)pxl * 64 + (g ^ (pxl & 7))) * 8] = u.v;
    }
  }
  __syncthreads();
  {
    const int pxl = tid & 31, gh = tid >> 5;  // gh 0..7
#pragma unroll
    for (int it = 0; it < 8; ++it) {
      int g = it * 8 + gh;
      uint4 v = *(const uint4*)&t[((size_t)pxl * 64 + (g ^ (pxl & 7))) * 8];
      *(uint4*)(xp + (((size_t)(b * 130 + y + 1) * 64 + g) * 130 + (px0 + pxl)) * 8) = v;
    }
  }
}

// ---- zero halo of a granule-major padded tensor [4][130][GPR][130][8] ------
__global__ __launch_bounds__(256) void zero_borders(
    unsigned short* __restrict__ p, int GPR) {
  int idx = blockIdx.x * 256 + threadIdx.x;   // 4*130*GPR*130 exactly
  int px = idx % 130;
  int t = idx / 130;
  int g = t % GPR;
  int tt = t / GPR;
  int y = tt % 130;
  int b = tt / 130;
  if (b < 4 && (px == 0 || px == 129 || y == 0 || y == 129))
    *(uint4*)(p + (((size_t)(b * 130 + y) * GPR + g) * 130 + px) * 8) =
        make_uint4(0u, 0u, 0u, 0u);
}

// ---- 3x3 conv, phase-split implicit GEMM, bf16 MFMA 32x32x16 ---------------
// Ap:  granule-major [4][130][CIN/8][130][8] bf16 (zero halo).
// WTp: packed [3*NCI blocks][(dx*4+q)*256+co][8] bf16.
// Block tile: 256 px (2 rows x 128) x 256 cout; 8 waves 2Mx4N, wave 128x64,
// acc[4][2].  K-loop: tile t = (dy, kt), BK=32; 3 phases (dx) per tile.
// Per phase: {ks0 reads | SB | ks1 reads ; [stage/vmcnt] ; barrier ;
//   lgkmcnt(6) ; MFMA ks0 ; lgkmcnt(0) ; MFMA ks1 ; barrier}  (ks-split T4)
// LDS (k-granule-major, conflict-free; verified 0 conflicts):
//   A: [rw*4+q][136 px][16B] = 17 408 B ; B: [dx*4+q][256 co][16B] = 49 152 B
//   double-buffered BUF=66 560 -> 133 120 B total.
template<int CIN, int MODE>
__global__ __launch_bounds__(512, 2) void conv3x3(
    const unsigned short* __restrict__ Ap,
    const unsigned short* __restrict__ WTp,
    const float* __restrict__ bias,
    unsigned short* __restrict__ out) {
  constexpr int NCI    = CIN / 32;
  constexpr int LOGNCI = (NCI == 16) ? 4 : 3;
  constexpr int NT     = 3 * NCI;
  constexpr int GPR    = CIN / 8;                 // granules per (y) row
  constexpr int PXS    = 136;                     // staged px per q-row
  constexpr int A_BYTES = 8 * PXS * 16;           // 17 408
  constexpr int B_BYTES = 12 * 256 * 16;          // 49 152
  constexpr int BUF     = A_BYTES + B_BYTES;      // 66 560
  __shared__ __align__(16) unsigned char smem[2 * BUF];

  const int tid  = threadIdx.x;
  const int wave = tid >> 6, lane = tid & 63;
  const int l31 = lane & 31, hi = lane >> 5;
  const int wm = wave >> 2, wn = wave & 3;        // 2M x 4N wave grid
  const int b = blockIdx.x >> 6;
  const int y0 = (blockIdx.x & 63) * 2;
  const int brow = b * 130 + y0;                  // input row at dy=0

  // ---- per-thread A staging decode (17 instrs, wave-strided s=wave+8i) ----
  int a_rel[3], a_c[3];
#pragma unroll
  for (int i = 0; i < 3; ++i) {
    int s = wave + i * 8;
    if (s < 17) {
      int c = s * 64 + lane;
      int px = c % PXS, t2 = c / PXS;
      int q = t2 & 3, rw = t2 >> 2;
      a_rel[i] = (rw * GPR + q) * 1040 + px * 8;
      a_c[i] = c * 16;
    } else { a_rel[i] = 0; a_c[i] = 0; }
  }

  // bias loads issued (and retired) before the pipeline's vmcnt counting
  const float bb0 = bias[wn * 64 + l31];
  const float bb1 = bias[wn * 64 + 32 + l31];

  f32x16 acc[4][2] = {};

  auto stage = [&](int tile) {
    const int dy = tile >> LOGNCI;
    const int kt = tile & (NCI - 1);
    unsigned char* sb = smem + (size_t)(tile & 1) * BUF;
    const unsigned short* Ab = Ap + ((size_t)(brow + dy) * GPR + kt * 4) * 1040;
    GLOAD_LDS16(Ab + a_rel[0], sb + a_c[0]);
    GLOAD_LDS16(Ab + a_rel[1], sb + a_c[1]);
    if (wave == 0) GLOAD_LDS16(Ab + a_rel[2], sb + a_c[2]);
    const unsigned short* Bb = WTp + (size_t)(dy * NCI + kt) * 24576;
#pragma unroll
    for (int i = 0; i < 6; ++i) {
      int c = (wave * 6 + i) * 64 + lane;
      GLOAD_LDS16(Bb + (size_t)c * 8, sb + A_BYTES + c * 16);
    }
  };

  // prologue: stage tile 0, publish
  stage(0);
  asm volatile("s_waitcnt vmcnt(0)" ::: "memory");
  __builtin_amdgcn_s_barrier();

#pragma unroll 2
  for (int t = 0; t < NT; ++t) {
    const unsigned char* sb = smem + (size_t)(t & 1) * BUF;
#pragma unroll
    for (int dx = 0; dx < 3; ++dx) {
      // ---- fragment reads, issue-order pinned: ks0 group then ks1 group ---
      bf16x8 af[2][4], bfr[2][2];
      {
        const int q_ = hi;                                      // ks = 0
        const int ab = ((wm * 4 + q_) * PXS + dx + l31) * 16;
        const int bb = A_BYTES + ((dx * 4 + q_) * 256 + wn * 64 + l31) * 16;
#pragma unroll
        for (int i = 0; i < 4; ++i)
          af[0][i] = *(const bf16x8*)(sb + ab + i * 512);
#pragma unroll
        for (int j = 0; j < 2; ++j)
          bfr[0][j] = *(const bf16x8*)(sb + bb + j * 512);
      }
      __builtin_amdgcn_sched_barrier(0);          // pin: ks0 reads issue first
      {
        const int q_ = 2 + hi;                                  // ks = 1
        const int ab = ((wm * 4 + q_) * PXS + dx + l31) * 16;
        const int bb = A_BYTES + ((dx * 4 + q_) * 256 + wn * 64 + l31) * 16;
#pragma unroll
        for (int i = 0; i < 4; ++i)
          af[1][i] = *(const bf16x8*)(sb + ab + i * 512);
#pragma unroll
        for (int j = 0; j < 2; ++j)
          bfr[1][j] = *(const bf16x8*)(sb + bb + j * 512);
      }
      // ---- staging schedule for tile t+1 ----------------------------------
      if (dx == 0 && t + 1 < NT) stage(t + 1);     // DMAs -> buf^1 (WAR-safe)
      if (dx == 2 && t + 1 < NT)                   // issued 2 phases ago: no stall
        asm volatile("s_waitcnt vmcnt(0)" ::: "memory");
      __builtin_amdgcn_sched_barrier(0);
      __builtin_amdgcn_s_barrier();                // (t,2): publishes buf t+1
      // ---- ks-split compute: MFMA ks0 overlaps ks1's LDS drain ------------
      asm volatile("s_waitcnt lgkmcnt(6)" ::: "memory");   // ks0 set resident
      __builtin_amdgcn_sched_barrier(0);
      __builtin_amdgcn_s_setprio(1);
#pragma unroll
      for (int i = 0; i < 4; ++i)
#pragma unroll
        for (int j = 0; j < 2; ++j)
          acc[i][j] = __builtin_amdgcn_mfma_f32_32x32x16_bf16(
              af[0][i], bfr[0][j], acc[i][j], 0, 0, 0);
      asm volatile("s_waitcnt lgkmcnt(0)" ::: "memory");   // ks1 set resident
      __builtin_amdgcn_sched_barrier(0);
#pragma unroll
      for (int i = 0; i < 4; ++i)
#pragma unroll
        for (int j = 0; j < 2; ++j)
          acc[i][j] = __builtin_amdgcn_mfma_f32_32x32x16_bf16(
              af[1][i], bfr[1][j], acc[i][j], 0, 0, 0);
      __builtin_amdgcn_s_setprio(0);
      __builtin_amdgcn_sched_barrier(0);
      __builtin_amdgcn_s_barrier();                // phase close
    }
  }

  // epilogue: 32x32 C/D layout: col = lane&31, row = (reg&3)+8*(reg>>2)+4*hi
#pragma unroll
  for (int i = 0; i < 4; ++i) {
#pragma unroll
    for (int j = 0; j < 2; ++j) {
      const int n = wn * 64 + j * 32 + l31;
      const float bb = j ? bb1 : bb0;
#pragma unroll
      for (int reg = 0; reg < 16; ++reg) {
        int px = i * 32 + (reg & 3) + 8 * (reg >> 2) + 4 * hi;
        float v = fmaxf(acc[i][j][reg] + bb, 0.f);
        size_t off;
        if (MODE == 0)    // h1_pad granule-major [b][y][32 g][130 px][8]
          off = (((size_t)(brow + wm + 1) * 32 + (n >> 3)) * 130 + (px + 1)) * 8 + (n & 7);
        else              // h2 flat NHWC [pix][256]
          off = ((size_t)((b * 128 + y0 + wm) * 128) + px) * 256 + n;
        out[off] = f2bf(v);
      }
    }
  }
}

// ---- heads: h2[65536][256] x WhT[54(pad 64)][256] + bias, softmax pairs ----
__global__ __launch_bounds__(256) void heads_kernel(
    const unsigned short* __restrict__ h2,
    const unsigned short* __restrict__ WhT,
    const float* __restrict__ br, const float* __restrict__ bc,
    float* __restrict__ out) {
  __shared__ __align__(16) unsigned short As[64][264];
  const int tid = threadIdx.x;
  const int wave = tid >> 6, lane = tid & 63;
  const int quad = lane >> 4, l16 = lane & 15;
  const int pix0 = blockIdx.x * 64;
#pragma unroll
  for (int r = 0; r < 8; ++r) {
    int s = r * 256 + tid;
    int row = s >> 5, seg = s & 31;                  // 64 rows x 32 x 16B
    *(uint4*)&As[row][seg * 8] =
        *(const uint4*)(h2 + (size_t)(pix0 + row) * 256 + seg * 8);
  }
  __syncthreads();
  f32x4 acc[4] = {};
#pragma unroll
  for (int ks = 0; ks < 8; ++ks) {
    bf16x8 af = *(const bf16x8*)&As[wave * 16 + l16][ks * 32 + quad * 8];
#pragma unroll
    for (int j = 0; j < 4; ++j) {
      bf16x8 bfr = *(const bf16x8*)(WhT + (size_t)(j * 16 + l16) * 256 + ks * 32 + quad * 8);
      acc[j] = __builtin_amdgcn_mfma_f32_16x16x32_bf16(af, bfr, acc[j], 0, 0, 0);
    }
  }
#pragma unroll
  for (int j = 0; j < 4; ++j) {
    int n = j * 16 + l16;                            // head channel (cls 0-17, reg 18-53)
    float bias = 0.f;
    if (n < 18) bias = bc[n];
    else if (n < 54) bias = br[n - 18];
#pragma unroll
    for (int r = 0; r < 4; ++r) {
      int p = pix0 + wave * 16 + quad * 4 + r;       // pixel
      float v = acc[j][r] + bias;
      float partner = __shfl_xor(v, 1);              // cls pair (even,odd lanes)
      if (n < 18) {
        float mx = fmaxf(v, partner);
        float e0 = __expf(v - mx), e1 = __expf(partner - mx);
        int a = n >> 1, sl = n & 1;
        out[(size_t)p * 54 + a * 6 + sl] = e0 / (e0 + e1);
      } else if (n < 54) {
        int rr = n - 18, a = rr >> 2, sl = (rr & 3) + 2;
        out[(size_t)p * 54 + a * 6 + sl] = v;
      }
    }
  }
}

// ---------------------------------------------------------------------------
extern "C" void kernel_launch(void* const* d_in, const int* in_sizes, int n_in,
                              void* d_out, int out_size, void* d_ws, size_t ws_size,
                              hipStream_t stream) {
  const float* x  = (const float*)d_in[0];
  const float* W1 = (const float*)d_in[1];
  const float* b1 = (const float*)d_in[2];
  const float* W2 = (const float*)d_in[3];
  const float* b2 = (const float*)d_in[4];
  const float* Wr = (const float*)d_in[5];
  const float* br = (const float*)d_in[6];
  const float* Wc = (const float*)d_in[7];
  const float* bc = (const float*)d_in[8];
  float* out = (float*)d_out;

  // workspace carve-up (bytes).  NOTE: conv3x3 A-staging over-reads up to
  // ~1 KB past x_pad / h1_pad row ends (136-px q-rows vs 130 stored); those
  // reads land in the NEXT buffer and are never consumed by MFMA.
  constexpr size_t XPAD_B  = 4ull * 130 * 130 * 512 * 2;   //  69,222,400
  constexpr size_t H1PAD_B = 4ull * 130 * 130 * 256 * 2;   //  34,611,200
  constexpr size_t H2_B    = 4ull * 128 * 128 * 256 * 2;   //  33,554,432
  constexpr size_t W1T_B   = 9ull * 256 * 512 * 2;         //   2,359,296
  constexpr size_t W2T_B   = 9ull * 256 * 256 * 2;         //   1,179,648
  char* ws = (char*)d_ws;
  unsigned short* x_pad  = (unsigned short*)(ws);
  unsigned short* h1_pad = (unsigned short*)(ws + XPAD_B);
  unsigned short* h2     = (unsigned short*)(ws + XPAD_B + H1PAD_B);
  unsigned short* W1T    = (unsigned short*)(ws + XPAD_B + H1PAD_B + H2_B);
  unsigned short* W2T    = (unsigned short*)(ws + XPAD_B + H1PAD_B + H2_B + W1T_B);
  unsigned short* WhT    = (unsigned short*)(ws + XPAD_B + H1PAD_B + H2_B + W1T_B + W2T_B);

  // zero the padded head-weight block (rows 54..63 are read by MFMA)
  hipMemsetAsync(WhT, 0, 64ull * 256 * 2, stream);
  // weight repacks: conv weights -> per-tile packed order; heads -> B^T
  pack_w<<<576, 256, 0, stream>>>(W1, W1T, 512);
  pack_w<<<288, 256, 0, stream>>>(W2, W2T, 256);
  transpose_cvt<<<dim3(8, 1, 1),  dim3(32, 8), 0, stream>>>(Wc, WhT, 256, 18);
  transpose_cvt<<<dim3(8, 2, 1),  dim3(32, 8), 0, stream>>>(Wr, WhT + 18 * 256, 256, 36);
  // input pad+convert (granule-major, LDS-transposed), halo zeros
  convert_x_t<<<2048, 256, 0, stream>>>(x, x_pad);
  zero_borders<<<16900, 256, 0, stream>>>(x_pad, 64);
  zero_borders<<<8450, 256, 0, stream>>>(h1_pad, 32);
  // conv1: 512ci -> h1_pad (granule-major) ; conv2: 256ci -> h2 flat
  conv3x3<512, 0><<<256, 512, 0, stream>>>(x_pad, W1T, b1, h1_pad);
  conv3x3<256, 1><<<256, 512, 0, stream>>>(h1_pad, W2T, b2, h2);
  // 1x1 heads + softmax + interleave
  heads_kernel<<<1024, 256, 0, stream>>>(h2, WhT, br, bc, out);
}

// Round 9
// 462.947 us; speedup vs baseline: 1.0201x; 1.0201x over previous
//
#include <hip/hip_runtime.h>

// ---------------------------------------------------------------------------
// RPN head on gfx950: x --conv3x3(512->256)+relu--> h1 --conv3x3(256->256)+relu
//   --> h2 --1x1 heads (cls 18 / reg 36)--> softmax pairs --> out (B,H,W,9,6)
// R10 = R8/R9 data layout (conflict-free k-granule LDS, packed weights,
// granule-major activations; verified 0 bank conflicts, no spill) with the
// barrier schedule cut from 6/tile to 1/tile:
//   all 3 dx-phases of a tile read the SAME LDS buffer (read-read, no hazard)
//   -> intra-tile barriers removed; per tile: 3x{12 ds_read; [dx0: stage t+1];
//   MFMA x16} ; vmcnt(0) ; s_barrier.  The tile-end barrier both publishes
//   buf t+1 (all waves' DMAs drained) and proves buf-t reads retired (each
//   wave's compiler-emitted lgkm waits precede its dx2 MFMAs).  Waves drift
//   within the tile: one wave's MFMA overlaps the other's LDS drain; the
//   compiler software-pipelines reads across phases with counted lgkmcnt.
// Also: border zeroing now exact-grid (774 blocks, 1 launch for both pads).
// ---------------------------------------------------------------------------

typedef float f32x4  __attribute__((ext_vector_type(4)));
typedef float f32x16 __attribute__((ext_vector_type(16)));
typedef short bf16x8 __attribute__((ext_vector_type(8)));   // 8 bf16 = 4 VGPRs

union U16x8 { uint4 v; unsigned short s[8]; };

__device__ __forceinline__ unsigned short f2bf(float f) {
  union { float f; unsigned int u; } v; v.f = f;
  unsigned int r = v.u + 0x7FFFu + ((v.u >> 16) & 1u);   // RNE
  return (unsigned short)(r >> 16);
}

#define GLOAD_LDS16(G, L)                                        \
  __builtin_amdgcn_global_load_lds(                              \
      (const __attribute__((address_space(1))) void*)(G),        \
      (__attribute__((address_space(3))) void*)(L), 16, 0, 0)

// ---- transpose + fp32->bf16: src[z][K][N] -> dst[z][N][K] (heads only) -----
__global__ __launch_bounds__(256) void transpose_cvt(
    const float* __restrict__ src, unsigned short* __restrict__ dst,
    int K, int N) {
  __shared__ float t[32][33];
  const int tx = threadIdx.x, ty = threadIdx.y;     // 32 x 8
  const int k0 = blockIdx.x * 32, n0 = blockIdx.y * 32;
  const float* s = src + (size_t)blockIdx.z * K * N;
  unsigned short* d = dst + (size_t)blockIdx.z * N * K;
#pragma unroll
  for (int r = 0; r < 32; r += 8) {
    int k = k0 + ty + r, n = n0 + tx;
    t[ty + r][tx] = (k < K && n < N) ? s[(size_t)k * N + n] : 0.f;
  }
  __syncthreads();
#pragma unroll
  for (int r = 0; r < 32; r += 8) {
    int n = n0 + ty + r, k = k0 + tx;
    if (n < N && k < K) d[(size_t)n * K + k] = f2bf(t[tx][ty + r]);
  }
}

// ---- pack conv weights (3,3,CIN,256) f32 -> per-tile LDS order bf16 --------
// out[(dy*NCI+kt)*24576 + ((dx*4+q)*256+co)*8 + e] = W[dy][dx][kt*32+q*8+e][co]
__global__ __launch_bounds__(256) void pack_w(
    const float* __restrict__ W, unsigned short* __restrict__ out, int CIN) {
  const int NCI = CIN / 32;
  int tid = blockIdx.x * 256 + threadIdx.x;        // 9*NCI*1024 total
  int co = tid & 255;
  int q  = (tid >> 8) & 3;
  int t  = tid >> 10;
  int dx = t % 3;
  int r  = t / 3;
  int kt = r % NCI;
  int dy = r / NCI;
  U16x8 u;
#pragma unroll
  for (int e = 0; e < 8; ++e) {
    int ci = kt * 32 + q * 8 + e;
    u.s[e] = f2bf(W[((size_t)(dy * 3 + dx) * CIN + ci) * 256 + co]);
  }
  *(uint4*)(out + (size_t)tid * 8) = u.v;
}

// ---- x (f32 NHWC) -> x_pad interior (bf16 granule-major [4][130][64][130][8])
// LDS-transposed: coalesced reads (lanes over g), coalesced writes (lanes
// over px, 512-B runs).  XOR swizzle g^=(px&7): conflict-free both phases.
__global__ __launch_bounds__(256) void convert_x_t(
    const float* __restrict__ x, unsigned short* __restrict__ xp) {
  __shared__ __align__(16) unsigned short t[32 * 64 * 8];   // 32 px x 64 g
  const int tid = threadIdx.x;
  const int blk = blockIdx.x;            // b*512 + y*4 + pxblk
  const int pxb = blk & 3;
  const int y   = (blk >> 2) & 127;      // interior row (ypix = y+1)
  const int b   = blk >> 9;
  const int px0 = pxb * 32 + 1;          // output px 1..128
  {
    const int g = tid & 63, pl = tid >> 6;   // pl 0..3
#pragma unroll
    for (int it = 0; it < 8; ++it) {
      int pxl = it * 4 + pl;                 // 0..31
      const float* sp = x + ((size_t)((b * 128 + y) * 128) + (px0 - 1 + pxl)) * 512 + g * 8;
      float4 a = *(const float4*)sp;
      float4 c = *(const float4*)(sp + 4);
      U16x8 u;
      u.s[0] = f2bf(a.x); u.s[1] = f2bf(a.y); u.s[2] = f2bf(a.z); u.s[3] = f2bf(a.w);
      u.s[4] = f2bf(c.x); u.s[5] = f2bf(c.y); u.s[6] = f2bf(c.z); u.s[7] = f2bf(c.w);
      *(uint4*)&t[((size_t)pxl * 64 + (g ^ (pxl & 7))) * 8] = u.v;
    }
  }
  __syncthreads();
  {
    const int pxl = tid & 31, gh = tid >> 5;  // gh 0..7
#pragma unroll
    for (int it = 0; it < 8; ++it) {
      int g = it * 8 + gh;
      uint4 v = *(const uint4*)&t[((size_t)pxl * 64 + (g ^ (pxl & 7))) * 8];
      *(uint4*)(xp + (((size_t)(b * 130 + y + 1) * 64 + g) * 130 + (px0 + pxl)) * 8) = v;
    }
  }
}

// ---- zero halos of x_pad (GPR=64) and h1_pad (GPR=32), exact-border grid ---
// ring r: 0..129 (y=0), 130..259 (y=129), 260..387 (px=0), 388..515 (px=129)
__global__ __launch_bounds__(256) void zero_halos(
    unsigned short* __restrict__ xp, unsigned short* __restrict__ h1p) {
  int idx = blockIdx.x * 256 + threadIdx.x;   // 132096 + 66048 = 198144 exactly
  unsigned short* p; int gpr, rem;
  if (idx < 132096) { p = xp; gpr = 64; rem = idx; }
  else              { p = h1p; gpr = 32; rem = idx - 132096; }
  int r = rem % 516;
  int t = rem / 516;
  int g = t % gpr;
  int b = t / gpr;
  int y, px;
  if (r < 260) { y = (r < 130) ? 0 : 129; px = (r < 130) ? r : r - 130; }
  else         { px = (r < 388) ? 0 : 129; y = (r < 388) ? (r - 259) : (r - 387); }
  *(uint4*)(p + (((size_t)(b * 130 + y) * gpr + g) * 130 + px) * 8) =
      make_uint4(0u, 0u, 0u, 0u);
}

// ---- 3x3 conv, drift-scheduled implicit GEMM, bf16 MFMA 32x32x16 -----------
// Ap:  granule-major [4][130][CIN/8][130][8] bf16 (zero halo).
// WTp: packed [3*NCI blocks][(dx*4+q)*256+co][8] bf16.
// Block tile: 256 px (2 rows x 128) x 256 cout; 8 waves 2Mx4N, wave 128x64,
// acc[4][2].  K-loop: tile t = (dy, kt), BK=32; 3 dx-phases per tile,
// ONE barrier per tile (see header).  LDS (k-granule-major, conflict-free):
//   A: [rw*4+q][136 px][16B] = 17 408 B ; B: [dx*4+q][256 co][16B] = 49 152 B
//   double-buffered BUF=66 560 -> 133 120 B total.
template<int CIN, int MODE>
__global__ __launch_bounds__(512, 2) void conv3x3(
    const unsigned short* __restrict__ Ap,
    const unsigned short* __restrict__ WTp,
    const float* __restrict__ bias,
    unsigned short* __restrict__ out) {
  constexpr int NCI    = CIN / 32;
  constexpr int LOGNCI = (NCI == 16) ? 4 : 3;
  constexpr int NT     = 3 * NCI;
  constexpr int GPR    = CIN / 8;                 // granules per (y) row
  constexpr int PXS    = 136;                     // staged px per q-row
  constexpr int A_BYTES = 8 * PXS * 16;           // 17 408
  constexpr int B_BYTES = 12 * 256 * 16;          // 49 152
  constexpr int BUF     = A_BYTES + B_BYTES;      // 66 560
  __shared__ __align__(16) unsigned char smem[2 * BUF];

  const int tid  = threadIdx.x;
  const int wave = tid >> 6, lane = tid & 63;
  const int l31 = lane & 31, hi = lane >> 5;
  const int wm = wave >> 2, wn = wave & 3;        // 2M x 4N wave grid
  const int b = blockIdx.x >> 6;
  const int y0 = (blockIdx.x & 63) * 2;
  const int brow = b * 130 + y0;                  // input row at dy=0

  // ---- per-thread A staging decode (17 instrs, wave-strided s=wave+8i) ----
  int a_rel[3], a_c[3];
#pragma unroll
  for (int i = 0; i < 3; ++i) {
    int s = wave + i * 8;
    if (s < 17) {
      int c = s * 64 + lane;
      int px = c % PXS, t2 = c / PXS;
      int q = t2 & 3, rw = t2 >> 2;
      a_rel[i] = (rw * GPR + q) * 1040 + px * 8;
      a_c[i] = c * 16;
    } else { a_rel[i] = 0; a_c[i] = 0; }
  }

  // bias loads issued (and retired) before the pipeline's vmcnt counting
  const float bb0 = bias[wn * 64 + l31];
  const float bb1 = bias[wn * 64 + 32 + l31];

  f32x16 acc[4][2] = {};

  auto stage = [&](int tile) {
    const int dy = tile >> LOGNCI;
    const int kt = tile & (NCI - 1);
    unsigned char* sb = smem + (size_t)(tile & 1) * BUF;
    const unsigned short* Ab = Ap + ((size_t)(brow + dy) * GPR + kt * 4) * 1040;
    GLOAD_LDS16(Ab + a_rel[0], sb + a_c[0]);
    GLOAD_LDS16(Ab + a_rel[1], sb + a_c[1]);
    if (wave == 0) GLOAD_LDS16(Ab + a_rel[2], sb + a_c[2]);
    const unsigned short* Bb = WTp + (size_t)(dy * NCI + kt) * 24576;
#pragma unroll
    for (int i = 0; i < 6; ++i) {
      int c = (wave * 6 + i) * 64 + lane;
      GLOAD_LDS16(Bb + (size_t)c * 8, sb + A_BYTES + c * 16);
    }
  };

  // prologue: stage tile 0, publish
  stage(0);
  asm volatile("s_waitcnt vmcnt(0)" ::: "memory");
  __builtin_amdgcn_s_barrier();

#pragma unroll 2
  for (int t = 0; t < NT; ++t) {
    const unsigned char* sb = smem + (size_t)(t & 1) * BUF;
#pragma unroll
    for (int dx = 0; dx < 3; ++dx) {
      // fragment reads (buf t; conflict-free contiguous).  No barrier needed:
      // all 3 phases read the same buffer; compiler emits counted lgkm waits.
      bf16x8 af[2][4], bfr[2][2];
#pragma unroll
      for (int ks = 0; ks < 2; ++ks) {
        const int q_ = ks * 2 + hi;
        const int ab = ((wm * 4 + q_) * PXS + dx + l31) * 16;
        const int bb = A_BYTES + ((dx * 4 + q_) * 256 + wn * 64 + l31) * 16;
#pragma unroll
        for (int i = 0; i < 4; ++i)
          af[ks][i] = *(const bf16x8*)(sb + ab + i * 512);
#pragma unroll
        for (int j = 0; j < 2; ++j)
          bfr[ks][j] = *(const bf16x8*)(sb + bb + j * 512);
      }
      if (dx == 0 && t + 1 < NT) stage(t + 1);   // DMAs -> buf^1 (WAR-safe:
                                                 // prior reads of that buffer
                                                 // retired before last barrier)
      __builtin_amdgcn_s_setprio(1);
#pragma unroll
      for (int ks = 0; ks < 2; ++ks)
#pragma unroll
        for (int i = 0; i < 4; ++i)
#pragma unroll
          for (int j = 0; j < 2; ++j)
            acc[i][j] = __builtin_amdgcn_mfma_f32_32x32x16_bf16(
                af[ks][i], bfr[ks][j], acc[i][j], 0, 0, 0);
      __builtin_amdgcn_s_setprio(0);
    }
    // tile end: single barrier publishes buf t+1 (vmcnt(0) drains this tile's
    // DMAs) AND proves buf-t reads retired (lgkm waits preceded dx2 MFMAs).
    asm volatile("s_waitcnt vmcnt(0)" ::: "memory");
    __builtin_amdgcn_s_barrier();
  }

  // epilogue: 32x32 C/D layout: col = lane&31, row = (reg&3)+8*(reg>>2)+4*hi
#pragma unroll
  for (int i = 0; i < 4; ++i) {
#pragma unroll
    for (int j = 0; j < 2; ++j) {
      const int n = wn * 64 + j * 32 + l31;
      const float bb = j ? bb1 : bb0;
#pragma unroll
      for (int reg = 0; reg < 16; ++reg) {
        int px = i * 32 + (reg & 3) + 8 * (reg >> 2) + 4 * hi;
        float v = fmaxf(acc[i][j][reg] + bb, 0.f);
        size_t off;
        if (MODE == 0)    // h1_pad granule-major [b][y][32 g][130 px][8]
          off = (((size_t)(brow + wm + 1) * 32 + (n >> 3)) * 130 + (px + 1)) * 8 + (n & 7);
        else              // h2 flat NHWC [pix][256]
          off = ((size_t)((b * 128 + y0 + wm) * 128) + px) * 256 + n;
        out[off] = f2bf(v);
      }
    }
  }
}

// ---- heads: h2[65536][256] x WhT[54(pad 64)][256] + bias, softmax pairs ----
__global__ __launch_bounds__(256) void heads_kernel(
    const unsigned short* __restrict__ h2,
    const unsigned short* __restrict__ WhT,
    const float* __restrict__ br, const float* __restrict__ bc,
    float* __restrict__ out) {
  __shared__ __align__(16) unsigned short As[64][264];
  const int tid = threadIdx.x;
  const int wave = tid >> 6, lane = tid & 63;
  const int quad = lane >> 4, l16 = lane & 15;
  const int pix0 = blockIdx.x * 64;
#pragma unroll
  for (int r = 0; r < 8; ++r) {
    int s = r * 256 + tid;
    int row = s >> 5, seg = s & 31;                  // 64 rows x 32 x 16B
    *(uint4*)&As[row][seg * 8] =
        *(const uint4*)(h2 + (size_t)(pix0 + row) * 256 + seg * 8);
  }
  __syncthreads();
  f32x4 acc[4] = {};
#pragma unroll
  for (int ks = 0; ks < 8; ++ks) {
    bf16x8 af = *(const bf16x8*)&As[wave * 16 + l16][ks * 32 + quad * 8];
#pragma unroll
    for (int j = 0; j < 4; ++j) {
      bf16x8 bfr = *(const bf16x8*)(WhT + (size_t)(j * 16 + l16) * 256 + ks * 32 + quad * 8);
      acc[j] = __builtin_amdgcn_mfma_f32_16x16x32_bf16(af, bfr, acc[j], 0, 0, 0);
    }
  }
#pragma unroll
  for (int j = 0; j < 4; ++j) {
    int n = j * 16 + l16;                            // head channel (cls 0-17, reg 18-53)
    float bias = 0.f;
    if (n < 18) bias = bc[n];
    else if (n < 54) bias = br[n - 18];
#pragma unroll
    for (int r = 0; r < 4; ++r) {
      int p = pix0 + wave * 16 + quad * 4 + r;       // pixel
      float v = acc[j][r] + bias;
      float partner = __shfl_xor(v, 1);              // cls pair (even,odd lanes)
      if (n < 18) {
        float mx = fmaxf(v, partner);
        float e0 = __expf(v - mx), e1 = __expf(partner - mx);
        int a = n >> 1, sl = n & 1;
        out[(size_t)p * 54 + a * 6 + sl] = e0 / (e0 + e1);
      } else if (n < 54) {
        int rr = n - 18, a = rr >> 2, sl = (rr & 3) + 2;
        out[(size_t)p * 54 + a * 6 + sl] = v;
      }
    }
  }
}

// ---------------------------------------------------------------------------
extern "C" void kernel_launch(void* const* d_in, const int* in_sizes, int n_in,
                              void* d_out, int out_size, void* d_ws, size_t ws_size,
                              hipStream_t stream) {
  const float* x  = (const float*)d_in[0];
  const float* W1 = (const float*)d_in[1];
  const float* b1 = (const float*)d_in[2];
  const float* W2 = (const float*)d_in[3];
  const float* b2 = (const float*)d_in[4];
  const float* Wr = (const float*)d_in[5];
  const float* br = (const float*)d_in[6];
  const float* Wc = (const float*)d_in[7];
  const float* bc = (const float*)d_in[8];
  float* out = (float*)d_out;

  // workspace carve-up (bytes).  NOTE: conv3x3 A-staging over-reads up to
  // ~1 KB past x_pad / h1_pad row ends (136-px q-rows vs 130 stored); those
  // reads land in the NEXT buffer and are never consumed by MFMA.
  constexpr size_t XPAD_B  = 4ull * 130 * 130 * 512 * 2;   //  69,222,400
  constexpr size_t H1PAD_B = 4ull * 130 * 130 * 256 * 2;   //  34,611,200
  constexpr size_t H2_B    = 4ull * 128 * 128 * 256 * 2;   //  33,554,432
  constexpr size_t W1T_B   = 9ull * 256 * 512 * 2;         //   2,359,296
  constexpr size_t W2T_B   = 9ull * 256 * 256 * 2;         //   1,179,648
  char* ws = (char*)d_ws;
  unsigned short* x_pad  = (unsigned short*)(ws);
  unsigned short* h1_pad = (unsigned short*)(ws + XPAD_B);
  unsigned short* h2     = (unsigned short*)(ws + XPAD_B + H1PAD_B);
  unsigned short* W1T    = (unsigned short*)(ws + XPAD_B + H1PAD_B + H2_B);
  unsigned short* W2T    = (unsigned short*)(ws + XPAD_B + H1PAD_B + H2_B + W1T_B);
  unsigned short* WhT    = (unsigned short*)(ws + XPAD_B + H1PAD_B + H2_B + W1T_B + W2T_B);

  // zero the padded head-weight block (rows 54..63 are read by MFMA)
  hipMemsetAsync(WhT, 0, 64ull * 256 * 2, stream);
  // weight repacks: conv weights -> per-tile packed order; heads -> B^T
  pack_w<<<576, 256, 0, stream>>>(W1, W1T, 512);
  pack_w<<<288, 256, 0, stream>>>(W2, W2T, 256);
  transpose_cvt<<<dim3(8, 1, 1),  dim3(32, 8), 0, stream>>>(Wc, WhT, 256, 18);
  transpose_cvt<<<dim3(8, 2, 1),  dim3(32, 8), 0, stream>>>(Wr, WhT + 18 * 256, 256, 36);
  // input pad+convert (granule-major, LDS-transposed), exact-border halo zero
  convert_x_t<<<2048, 256, 0, stream>>>(x, x_pad);
  zero_halos<<<774, 256, 0, stream>>>(x_pad, h1_pad);
  // conv1: 512ci -> h1_pad (granule-major) ; conv2: 256ci -> h2 flat
  conv3x3<512, 0><<<256, 512, 0, stream>>>(x_pad, W1T, b1, h1_pad);
  conv3x3<256, 1><<<256, 512, 0, stream>>>(h1_pad, W2T, b2, h2);
  // 1x1 heads + softmax + interleave
  heads_kernel<<<1024, 256, 0, stream>>>(h2, WhT, br, bc, out);
}